// Round 2
// baseline (150.688 us; speedup 1.0000x reference)
//
#include <hip/hip_runtime.h>
#include <stdint.h>

typedef __bf16    bf16x8  __attribute__((ext_vector_type(8)));
typedef float     f32x16v __attribute__((ext_vector_type(16)));
typedef float     f32x4v  __attribute__((ext_vector_type(4)));
typedef uint32_t  u32x4v  __attribute__((ext_vector_type(4)));
typedef unsigned short u16;

__device__ __forceinline__ u16 f32_to_bf16_rne(float f) {
  uint32_t u = __builtin_bit_cast(uint32_t, f);
  return (u16)((u + 0x7fffu + ((u >> 16) & 1u)) >> 16);
}

__device__ __forceinline__ u32x4v pack_bf16x8(f32x4v a, f32x4v b) {
  uint32_t p0, p1, p2, p3;
  asm("v_cvt_pk_bf16_f32 %0, %1, %2" : "=v"(p0) : "v"(a[0]), "v"(a[1]));
  asm("v_cvt_pk_bf16_f32 %0, %1, %2" : "=v"(p1) : "v"(a[2]), "v"(a[3]));
  asm("v_cvt_pk_bf16_f32 %0, %1, %2" : "=v"(p2) : "v"(b[0]), "v"(b[1]));
  asm("v_cvt_pk_bf16_f32 %0, %1, %2" : "=v"(p3) : "v"(b[2]), "v"(b[3]));
  u32x4v r; r[0] = p0; r[1] = p1; r[2] = p2; r[3] = p3; return r;
}

__device__ __forceinline__ f32x16v mfma16(u32x4v a, u32x4v b, f32x16v c) {
  return __builtin_amdgcn_mfma_f32_32x32x16_bf16(
      __builtin_bit_cast(bf16x8, a), __builtin_bit_cast(bf16x8, b), c, 0, 0, 0);
}

// prep: W f32 [65][i=64][k=64]  ->  w1t bf16 [65][k][i]  and  w2b bf16 [65][i][k]
__global__ __launch_bounds__(256) void prep_w(const float* __restrict__ W,
                                              u16* __restrict__ w1t,
                                              u16* __restrict__ w2b) {
  __shared__ u16 tile[64 * 65];
  const int j = blockIdx.x;
  const int t = threadIdx.x;
  const float* Wj = W + j * 4096;
  for (int idx = t; idx < 4096; idx += 256) {
    u16 us = f32_to_bf16_rne(Wj[idx]);
    w2b[j * 4096 + idx] = us;
    tile[(idx >> 6) * 65 + (idx & 63)] = us;   // tile[i][k]
  }
  __syncthreads();
  for (int idx = t; idx < 4096; idx += 256) {  // idx = k*64 + i
    w1t[j * 4096 + idx] = tile[(idx & 63) * 65 + (idx >> 6)];
  }
}

// main: grid 512 (2/CU), 512 thr (8 waves), BB=64 samples/block.
// wave = (kt: output-row tile of 32) x (jq: quarter of 65 j's).
// Samples live in the B operand columns: B-frags (g, then v) are constant
// registers across the j-loop; A = W stream; x1[b,j] folded post-MFMA.
__global__ __launch_bounds__(512, 4) void rquad_main(
    const float* __restrict__ x, const float* __restrict__ g,
    const u16* __restrict__ w1t, const u16* __restrict__ w2b,
    float* __restrict__ out) {
  __shared__ float x1f[64 * 67];   // x1 f32 [sample][j], stride 67 (conflict-free)
  __shared__ float vl [64 * 69];   // combine buffer [row][sample], stride 69

  const int t    = threadIdx.x;
  const int lane = t & 63;
  const int wv   = t >> 6;
  const int kt   = wv & 1;          // output-row tile (k rows for pass1, e rows for pass2)
  const int jq   = wv >> 1;         // j-quarter
  const int col  = lane & 31;
  const int half = lane >> 5;
  const long base = (long)blockIdx.x * 64;

  // fill x1 (f32) + zero combine buffer
  for (int idx = t; idx < 64 * 64; idx += 512) {
    int s = idx >> 6, c = idx & 63;
    x1f[s * 67 + c] = x[(base + s) * 64 + c];
  }
  if (t < 64) x1f[t * 67 + 64] = 1.0f;  // bias
  for (int idx = t; idx < 64 * 69; idx += 512) vl[idx] = 0.0f;

  // B-frags from g (bf16, constant across pass 1)
  // bf[bt][s] holds g[sample=bt*32+col, i = s*16 + half*8 + 0..7]
  u32x4v bfr[2][4];
  #pragma unroll
  for (int bt = 0; bt < 2; ++bt) {
    const float* gp = g + (base + bt * 32 + col) * 64 + half * 8;
    #pragma unroll
    for (int s = 0; s < 4; ++s) {
      f32x4v a = *reinterpret_cast<const f32x4v*>(gp + s * 16);
      f32x4v b = *reinterpret_cast<const f32x4v*>(gp + s * 16 + 4);
      bfr[bt][s] = pack_bf16x8(a, b);
    }
  }

  const int j0 = jq * 16;
  const int j1 = (jq == 3) ? 65 : (j0 + 16);

  f32x16v vacc[2];

  __syncthreads();

  auto run_pass = [&](const u16* __restrict__ Wsrc) {
    #pragma unroll
    for (int bt = 0; bt < 2; ++bt)
      #pragma unroll
      for (int r = 0; r < 16; ++r) vacc[bt][r] = 0.0f;

    // A-frag: row = kt*32+col (output row), K = i (or k), contiguous 8 bf16
    const u16* wrow = Wsrc + (kt * 32 + col) * 64 + half * 8;

    for (int jj = j0; jj < j1; ++jj) {
      const u16* wj = wrow + jj * 4096;
      u32x4v a0 = *reinterpret_cast<const u32x4v*>(wj);
      u32x4v a1 = *reinterpret_cast<const u32x4v*>(wj + 16);
      u32x4v a2 = *reinterpret_cast<const u32x4v*>(wj + 32);
      u32x4v a3 = *reinterpret_cast<const u32x4v*>(wj + 48);
      #pragma unroll
      for (int bt = 0; bt < 2; ++bt) {
        float x1v = x1f[(bt * 32 + col) * 67 + jj];  // per-lane uniform over r
        f32x16v T;
        T = mfma16(a0, bfr[bt][0], (f32x16v)(0.0f));  // src2 = inline 0
        T = mfma16(a1, bfr[bt][1], T);
        T = mfma16(a2, bfr[bt][2], T);
        T = mfma16(a3, bfr[bt][3], T);
        #pragma unroll
        for (int r = 0; r < 16; ++r)
          vacc[bt][r] = fmaf(x1v, T[r], vacc[bt][r]);
      }
    }
  };

  // ---------------- pass 1: v[k,b] = sum_j x1[b,j] * (W1[j]^T g)[k,b] ----------------
  run_pass(w1t);

  #pragma unroll
  for (int bt = 0; bt < 2; ++bt)
    #pragma unroll
    for (int r = 0; r < 16; ++r) {
      const int rr = (r & 3) + 8 * (r >> 2) + 4 * half;
      atomicAdd(&vl[(kt * 32 + rr) * 69 + bt * 32 + col], vacc[bt][r]);
    }
  __syncthreads();

  // rebuild B-frags from v (f32 -> bf16)
  #pragma unroll
  for (int bt = 0; bt < 2; ++bt) {
    #pragma unroll
    for (int s = 0; s < 4; ++s) {
      f32x4v a, b;
      #pragma unroll
      for (int e = 0; e < 4; ++e)
        a[e] = vl[(s * 16 + half * 8 + e) * 69 + bt * 32 + col];
      #pragma unroll
      for (int e = 0; e < 4; ++e)
        b[e] = vl[(s * 16 + half * 8 + 4 + e) * 69 + bt * 32 + col];
      bfr[bt][s] = pack_bf16x8(a, b);
    }
  }
  __syncthreads();
  for (int idx = t; idx < 64 * 69; idx += 512) vl[idx] = 0.0f;
  __syncthreads();

  // ---------------- pass 2: out[e,b] = (1/8) sum_j x1[b,j] * (W2[j] v)[e,b] ----------------
  run_pass(w2b);

  #pragma unroll
  for (int bt = 0; bt < 2; ++bt)
    #pragma unroll
    for (int r = 0; r < 16; ++r) {
      const int rr = (r & 3) + 8 * (r >> 2) + 4 * half;
      atomicAdd(&vl[(kt * 32 + rr) * 69 + bt * 32 + col], vacc[bt][r]);
    }
  __syncthreads();

  for (int idx = t; idx < 64 * 64; idx += 512) {
    int s = idx >> 6, e = idx & 63;
    out[(base + s) * 64 + e] = vl[e * 69 + s] * 0.125f;
  }
}

extern "C" void kernel_launch(void* const* d_in, const int* in_sizes, int n_in,
                              void* d_out, int out_size, void* d_ws, size_t ws_size,
                              hipStream_t stream) {
  const float* x = (const float*)d_in[0];
  const float* g = (const float*)d_in[1];
  const float* W = (const float*)d_in[2];
  float* o = (float*)d_out;
  u16* w1t = (u16*)d_ws;                    // 65*4096 bf16 = 520 KiB
  u16* w2b = w1t + 65 * 4096;               // another 520 KiB
  hipLaunchKernelGGL(prep_w, dim3(65), dim3(256), 0, stream, W, w1t, w2b);
  hipLaunchKernelGGL(rquad_main, dim3(512), dim3(512), 0, stream, x, g, w1t, w2b, o);
}

// Round 3
// 144.368 us; speedup vs baseline: 1.0438x; 1.0438x over previous
//
#include <hip/hip_runtime.h>
#include <stdint.h>

typedef __bf16    bf16x8  __attribute__((ext_vector_type(8)));
typedef float     f32x16v __attribute__((ext_vector_type(16)));
typedef float     f32x4v  __attribute__((ext_vector_type(4)));
typedef uint32_t  u32x4v  __attribute__((ext_vector_type(4)));
typedef unsigned short u16;

__device__ __forceinline__ u16 f32_to_bf16_rne(float f) {
  uint32_t u = __builtin_bit_cast(uint32_t, f);
  return (u16)((u + 0x7fffu + ((u >> 16) & 1u)) >> 16);
}

__device__ __forceinline__ u32x4v pack_bf16x8(f32x4v a, f32x4v b) {
  uint32_t p0, p1, p2, p3;
  asm("v_cvt_pk_bf16_f32 %0, %1, %2" : "=v"(p0) : "v"(a[0]), "v"(a[1]));
  asm("v_cvt_pk_bf16_f32 %0, %1, %2" : "=v"(p1) : "v"(a[2]), "v"(a[3]));
  asm("v_cvt_pk_bf16_f32 %0, %1, %2" : "=v"(p2) : "v"(b[0]), "v"(b[1]));
  asm("v_cvt_pk_bf16_f32 %0, %1, %2" : "=v"(p3) : "v"(b[2]), "v"(b[3]));
  u32x4v r; r[0] = p0; r[1] = p1; r[2] = p2; r[3] = p3; return r;
}

__device__ __forceinline__ f32x16v mfma16(u32x4v a, u32x4v b, f32x16v c) {
  return __builtin_amdgcn_mfma_f32_32x32x16_bf16(
      __builtin_bit_cast(bf16x8, a), __builtin_bit_cast(bf16x8, b), c, 0, 0, 0);
}

// prep: W f32 [65][i=64][k=64] -> fragment-major bf16 arrays.
// Chunk layout: elem idx = jj*4096 + (kt*4+s)*512 + l*8 + e  (l = lane 0..63)
//   w1f (pass1 A = W^T per j): value = W[jj][ i=s*16+(l>>5)*8+e ][ k=kt*32+(l&31) ]
//   w2f (pass2 A = W per j)  : value = W[jj][ e_row=kt*32+(l&31) ][ k=s*16+(l>>5)*8+e ]
__global__ __launch_bounds__(256) void prep_w(const float* __restrict__ W,
                                              u16* __restrict__ w1f,
                                              u16* __restrict__ w2f) {
  __shared__ float Wl[4096];
  const int jj = blockIdx.x;
  const int t  = threadIdx.x;
  for (int idx = t; idx < 4096; idx += 256) Wl[idx] = W[jj * 4096 + idx];
  __syncthreads();
  for (int p = t; p < 512; p += 256) {      // p = (kt*4+s)*64 + l
    const int c  = p >> 6, l = p & 63;
    const int kt = c >> 2, s = c & 3;
    const int rowA = kt * 32 + (l & 31);
    const int k0   = s * 16 + (l >> 5) * 8;
    u16 v1[8], v2[8];
    #pragma unroll
    for (int e = 0; e < 8; ++e) {
      v2[e] = f32_to_bf16_rne(Wl[rowA * 64 + k0 + e]);
      v1[e] = f32_to_bf16_rne(Wl[(k0 + e) * 64 + rowA]);
    }
    u32x4v pk1, pk2;
    #pragma unroll
    for (int q = 0; q < 4; ++q) {
      pk1[q] = (uint32_t)v1[2*q] | ((uint32_t)v1[2*q+1] << 16);
      pk2[q] = (uint32_t)v2[2*q] | ((uint32_t)v2[2*q+1] << 16);
    }
    *reinterpret_cast<u32x4v*>(w1f + jj * 4096 + p * 8) = pk1;
    *reinterpret_cast<u32x4v*>(w2f + jj * 4096 + p * 8) = pk2;
  }
}

// main: grid 512 (2/CU), 512 thr (8 waves), BB=64 samples/block.
// wave = (kt: output-row tile of 32) x (jq: quarter of 65 j's).
// Samples in B operand (constant regs across j-loop); A = fragment-major W
// stream (every load = contiguous 1KB wave-load); x1[b,j] folded post-MFMA.
__global__ __launch_bounds__(512, 2) void rquad_main(
    const float* __restrict__ x, const float* __restrict__ g,
    const u16* __restrict__ w1f, const u16* __restrict__ w2f,
    float* __restrict__ out) {
  __shared__ float x1f[64 * 67];   // x1 f32 [sample][j]
  __shared__ float vl [64 * 69];   // combine buffer [row][sample]

  const int t    = threadIdx.x;
  const int lane = t & 63;
  const int wv   = t >> 6;
  const int kt   = wv & 1;
  const int jq   = wv >> 1;
  const int col  = lane & 31;
  const int half = lane >> 5;
  const long base = (long)blockIdx.x * 64;

  for (int idx = t; idx < 64 * 64; idx += 512) {
    int s = idx >> 6, c = idx & 63;
    x1f[s * 67 + c] = x[(base + s) * 64 + c];
  }
  if (t < 64) x1f[t * 67 + 64] = 1.0f;
  for (int idx = t; idx < 64 * 69; idx += 512) vl[idx] = 0.0f;

  // B-frags from g: bfr[bt][s] = g[sample=bt*32+col, i=s*16+half*8 ..+8]
  u32x4v bfr[2][4];
  #pragma unroll
  for (int bt = 0; bt < 2; ++bt) {
    const float* gp = g + (base + bt * 32 + col) * 64 + half * 8;
    #pragma unroll
    for (int s = 0; s < 4; ++s) {
      f32x4v a = *reinterpret_cast<const f32x4v*>(gp + s * 16);
      f32x4v b = *reinterpret_cast<const f32x4v*>(gp + s * 16 + 4);
      bfr[bt][s] = pack_bf16x8(a, b);
    }
  }

  const int j0 = jq * 16;
  const int j1 = (jq == 3) ? 65 : (j0 + 16);

  f32x16v vacc[2];

  __syncthreads();

  auto run_pass = [&](const u16* __restrict__ Wsrc) {
    #pragma unroll
    for (int bt = 0; bt < 2; ++bt)
      #pragma unroll
      for (int r = 0; r < 16; ++r) vacc[bt][r] = 0.0f;

    // per-lane A pointer: chunk (jj, kt, s), contiguous 16B at lane*16
    const u16* wbase = Wsrc + kt * 2048 + lane * 8;

    for (int jj = j0; jj < j1; ++jj) {
      const u16* wj = wbase + jj * 4096;
      u32x4v a0 = *reinterpret_cast<const u32x4v*>(wj);
      u32x4v a1 = *reinterpret_cast<const u32x4v*>(wj + 512);
      u32x4v a2 = *reinterpret_cast<const u32x4v*>(wj + 1024);
      u32x4v a3 = *reinterpret_cast<const u32x4v*>(wj + 1536);
      #pragma unroll
      for (int bt = 0; bt < 2; ++bt) {
        float x1v = x1f[(bt * 32 + col) * 67 + jj];
        f32x16v T;
        T = mfma16(a0, bfr[bt][0], (f32x16v)(0.0f));
        T = mfma16(a1, bfr[bt][1], T);
        T = mfma16(a2, bfr[bt][2], T);
        T = mfma16(a3, bfr[bt][3], T);
        #pragma unroll
        for (int r = 0; r < 16; ++r)
          vacc[bt][r] = fmaf(x1v, T[r], vacc[bt][r]);
      }
    }
  };

  // ---------------- pass 1: v[k,b] ----------------
  run_pass(w1f);

  #pragma unroll
  for (int bt = 0; bt < 2; ++bt)
    #pragma unroll
    for (int r = 0; r < 16; ++r) {
      const int rr = (r & 3) + 8 * (r >> 2) + 4 * half;
      atomicAdd(&vl[(kt * 32 + rr) * 69 + bt * 32 + col], vacc[bt][r]);
    }
  __syncthreads();

  // rebuild B-frags from v
  #pragma unroll
  for (int bt = 0; bt < 2; ++bt) {
    #pragma unroll
    for (int s = 0; s < 4; ++s) {
      f32x4v a, b;
      #pragma unroll
      for (int e = 0; e < 4; ++e)
        a[e] = vl[(s * 16 + half * 8 + e) * 69 + bt * 32 + col];
      #pragma unroll
      for (int e = 0; e < 4; ++e)
        b[e] = vl[(s * 16 + half * 8 + 4 + e) * 69 + bt * 32 + col];
      bfr[bt][s] = pack_bf16x8(a, b);
    }
  }
  __syncthreads();
  for (int idx = t; idx < 64 * 69; idx += 512) vl[idx] = 0.0f;
  __syncthreads();

  // ---------------- pass 2: out[e,b] ----------------
  run_pass(w2f);

  #pragma unroll
  for (int bt = 0; bt < 2; ++bt)
    #pragma unroll
    for (int r = 0; r < 16; ++r) {
      const int rr = (r & 3) + 8 * (r >> 2) + 4 * half;
      atomicAdd(&vl[(kt * 32 + rr) * 69 + bt * 32 + col], vacc[bt][r]);
    }
  __syncthreads();

  for (int idx = t; idx < 64 * 64; idx += 512) {
    int s = idx >> 6, e = idx & 63;
    out[(base + s) * 64 + e] = vl[e * 69 + s] * 0.125f;
  }
}

extern "C" void kernel_launch(void* const* d_in, const int* in_sizes, int n_in,
                              void* d_out, int out_size, void* d_ws, size_t ws_size,
                              hipStream_t stream) {
  const float* x = (const float*)d_in[0];
  const float* g = (const float*)d_in[1];
  const float* W = (const float*)d_in[2];
  float* o = (float*)d_out;
  u16* w1f = (u16*)d_ws;                    // 65*4096 bf16 = 520 KiB
  u16* w2f = w1f + 65 * 4096;               // another 520 KiB
  hipLaunchKernelGGL(prep_w, dim3(65), dim3(256), 0, stream, W, w1f, w2f);
  hipLaunchKernelGGL(rquad_main, dim3(512), dim3(512), 0, stream, x, g, w1f, w2f, o);
}

// Round 4
// 134.786 us; speedup vs baseline: 1.1180x; 1.0711x over previous
//
#include <hip/hip_runtime.h>
#include <stdint.h>

typedef __bf16    bf16x8  __attribute__((ext_vector_type(8)));
typedef float     f32x16v __attribute__((ext_vector_type(16)));
typedef float     f32x4v  __attribute__((ext_vector_type(4)));
typedef uint32_t  u32x4v  __attribute__((ext_vector_type(4)));
typedef unsigned short u16;

__device__ __forceinline__ u16 f32_to_bf16_rne(float f) {
  uint32_t u = __builtin_bit_cast(uint32_t, f);
  return (u16)((u + 0x7fffu + ((u >> 16) & 1u)) >> 16);
}

__device__ __forceinline__ u32x4v pack_bf16x8(f32x4v a, f32x4v b) {
  uint32_t p0, p1, p2, p3;
  asm("v_cvt_pk_bf16_f32 %0, %1, %2" : "=v"(p0) : "v"(a[0]), "v"(a[1]));
  asm("v_cvt_pk_bf16_f32 %0, %1, %2" : "=v"(p1) : "v"(a[2]), "v"(a[3]));
  asm("v_cvt_pk_bf16_f32 %0, %1, %2" : "=v"(p2) : "v"(b[0]), "v"(b[1]));
  asm("v_cvt_pk_bf16_f32 %0, %1, %2" : "=v"(p3) : "v"(b[2]), "v"(b[3]));
  u32x4v r; r[0] = p0; r[1] = p1; r[2] = p2; r[3] = p3; return r;
}

__device__ __forceinline__ f32x16v mfma16(u32x4v a, u32x4v b, f32x16v c) {
  return __builtin_amdgcn_mfma_f32_32x32x16_bf16(
      __builtin_bit_cast(bf16x8, a), __builtin_bit_cast(bf16x8, b), c, 0, 0, 0);
}

// prep: W f32 [65][i=64][k=64] -> fragment-major bf16 arrays.
// elem idx = jj*4096 + (kt*4+s)*512 + l*8 + e  (l = lane)
//   w1f: W[jj][ i=s*16+(l>>5)*8+e ][ k=kt*32+(l&31) ]   (pass1 A = W^T)
//   w2f: W[jj][ e_row=kt*32+(l&31) ][ k=s*16+(l>>5)*8+e ] (pass2 A = W)
__global__ __launch_bounds__(256) void prep_w(const float* __restrict__ W,
                                              u16* __restrict__ w1f,
                                              u16* __restrict__ w2f) {
  __shared__ float Wl[4096];
  const int jj = blockIdx.x;
  const int t  = threadIdx.x;
  for (int idx = t; idx < 4096; idx += 256) Wl[idx] = W[jj * 4096 + idx];
  __syncthreads();
  for (int p = t; p < 512; p += 256) {
    const int c  = p >> 6, l = p & 63;
    const int kt = c >> 2, s = c & 3;
    const int rowA = kt * 32 + (l & 31);
    const int k0   = s * 16 + (l >> 5) * 8;
    u16 v1[8], v2[8];
    #pragma unroll
    for (int e = 0; e < 8; ++e) {
      v2[e] = f32_to_bf16_rne(Wl[rowA * 64 + k0 + e]);
      v1[e] = f32_to_bf16_rne(Wl[(k0 + e) * 64 + rowA]);
    }
    u32x4v pk1, pk2;
    #pragma unroll
    for (int q = 0; q < 4; ++q) {
      pk1[q] = (uint32_t)v1[2*q] | ((uint32_t)v1[2*q+1] << 16);
      pk2[q] = (uint32_t)v2[2*q] | ((uint32_t)v2[2*q+1] << 16);
    }
    *reinterpret_cast<u32x4v*>(w1f + jj * 4096 + p * 8) = pk1;
    *reinterpret_cast<u32x4v*>(w2f + jj * 4096 + p * 8) = pk2;
  }
}

// main: grid 512, 512 thr (8 waves), BB=64. wave = (kt x jq).
// NEW: per-block j-rotation (de-hotspot L2/L3) + 2-stream j loop (8
// outstanding 16B loads per wave before first waitcnt).
__global__ __launch_bounds__(512, 2) void rquad_main(
    const float* __restrict__ x, const float* __restrict__ g,
    const u16* __restrict__ w1f, const u16* __restrict__ w2f,
    float* __restrict__ out) {
  __shared__ float x1f[64 * 67];
  __shared__ float vl [64 * 69];

  const int t    = threadIdx.x;
  const int lane = t & 63;
  const int wv   = t >> 6;
  const int kt   = wv & 1;
  const int jq   = wv >> 1;
  const int col  = lane & 31;
  const int half = lane >> 5;
  const long base = (long)blockIdx.x * 64;
  const int rot  = (int)((blockIdx.x * 23u) % 65u);

  for (int idx = t; idx < 64 * 64; idx += 512) {
    int s = idx >> 6, c = idx & 63;
    x1f[s * 67 + c] = x[(base + s) * 64 + c];
  }
  if (t < 64) x1f[t * 67 + 64] = 1.0f;
  for (int idx = t; idx < 64 * 69; idx += 512) vl[idx] = 0.0f;

  // B-frags from g: bfr[bt][s] = g[sample=bt*32+col, i=s*16+half*8 ..+8]
  u32x4v bfr[2][4];
  #pragma unroll
  for (int bt = 0; bt < 2; ++bt) {
    const float* gp = g + (base + bt * 32 + col) * 64 + half * 8;
    #pragma unroll
    for (int s = 0; s < 4; ++s) {
      f32x4v a = *reinterpret_cast<const f32x4v*>(gp + s * 16);
      f32x4v b = *reinterpret_cast<const f32x4v*>(gp + s * 16 + 4);
      bfr[bt][s] = pack_bf16x8(a, b);
    }
  }

  f32x16v vacc[2];
  f32x16v Z;
  #pragma unroll
  for (int r = 0; r < 16; ++r) Z[r] = 0.0f;

  __syncthreads();

  const int j0 = jq * 16;

  auto do_j = [&](int jj, const u16* wbase) {
    const u16* wj = wbase + jj * 4096;
    u32x4v a0 = *reinterpret_cast<const u32x4v*>(wj);
    u32x4v a1 = *reinterpret_cast<const u32x4v*>(wj + 512);
    u32x4v a2 = *reinterpret_cast<const u32x4v*>(wj + 1024);
    u32x4v a3 = *reinterpret_cast<const u32x4v*>(wj + 1536);
    #pragma unroll
    for (int bt = 0; bt < 2; ++bt) {
      float x1v = x1f[(bt * 32 + col) * 67 + jj];
      f32x16v T;
      T = mfma16(a0, bfr[bt][0], Z);
      T = mfma16(a1, bfr[bt][1], T);
      T = mfma16(a2, bfr[bt][2], T);
      T = mfma16(a3, bfr[bt][3], T);
      #pragma unroll
      for (int r = 0; r < 16; ++r)
        vacc[bt][r] = fmaf(x1v, T[r], vacc[bt][r]);
    }
  };

  auto run_pass = [&](const u16* __restrict__ Wsrc) {
    #pragma unroll
    for (int bt = 0; bt < 2; ++bt)
      #pragma unroll
      for (int r = 0; r < 16; ++r) vacc[bt][r] = 0.0f;

    const u16* wbase = Wsrc + kt * 2048 + lane * 8;

    for (int i = 0; i < 8; ++i) {
      int jA = j0 + i + rot;      if (jA >= 65) jA -= 65;
      int jB = j0 + 8 + i + rot;  if (jB >= 65) jB -= 65;
      const u16* wA = wbase + jA * 4096;
      const u16* wB = wbase + jB * 4096;
      // issue all 8 loads before first use
      u32x4v a0 = *reinterpret_cast<const u32x4v*>(wA);
      u32x4v a1 = *reinterpret_cast<const u32x4v*>(wA + 512);
      u32x4v a2 = *reinterpret_cast<const u32x4v*>(wA + 1024);
      u32x4v a3 = *reinterpret_cast<const u32x4v*>(wA + 1536);
      u32x4v c0 = *reinterpret_cast<const u32x4v*>(wB);
      u32x4v c1 = *reinterpret_cast<const u32x4v*>(wB + 512);
      u32x4v c2 = *reinterpret_cast<const u32x4v*>(wB + 1024);
      u32x4v c3 = *reinterpret_cast<const u32x4v*>(wB + 1536);
      #pragma unroll
      for (int bt = 0; bt < 2; ++bt) {
        float xA = x1f[(bt * 32 + col) * 67 + jA];
        float xB = x1f[(bt * 32 + col) * 67 + jB];
        f32x16v T, U;
        T = mfma16(a0, bfr[bt][0], Z);
        U = mfma16(c0, bfr[bt][0], Z);
        T = mfma16(a1, bfr[bt][1], T);
        U = mfma16(c1, bfr[bt][1], U);
        T = mfma16(a2, bfr[bt][2], T);
        U = mfma16(c2, bfr[bt][2], U);
        T = mfma16(a3, bfr[bt][3], T);
        U = mfma16(c3, bfr[bt][3], U);
        #pragma unroll
        for (int r = 0; r < 16; ++r) {
          vacc[bt][r] = fmaf(xA, T[r], vacc[bt][r]);
          vacc[bt][r] = fmaf(xB, U[r], vacc[bt][r]);
        }
      }
    }
    if (jq == 3) {               // 17th j for the last quarter
      int jS = j0 + 16 + rot; if (jS >= 65) jS -= 65;
      do_j(jS, wbase);
    }
  };

  // ---------------- pass 1: v[k,b] ----------------
  run_pass(w1f);

  #pragma unroll
  for (int bt = 0; bt < 2; ++bt)
    #pragma unroll
    for (int r = 0; r < 16; ++r) {
      const int rr = (r & 3) + 8 * (r >> 2) + 4 * half;
      atomicAdd(&vl[(kt * 32 + rr) * 69 + bt * 32 + col], vacc[bt][r]);
    }
  __syncthreads();

  // rebuild B-frags from v
  #pragma unroll
  for (int bt = 0; bt < 2; ++bt) {
    #pragma unroll
    for (int s = 0; s < 4; ++s) {
      f32x4v a, b;
      #pragma unroll
      for (int e = 0; e < 4; ++e)
        a[e] = vl[(s * 16 + half * 8 + e) * 69 + bt * 32 + col];
      #pragma unroll
      for (int e = 0; e < 4; ++e)
        b[e] = vl[(s * 16 + half * 8 + 4 + e) * 69 + bt * 32 + col];
      bfr[bt][s] = pack_bf16x8(a, b);
    }
  }
  __syncthreads();
  for (int idx = t; idx < 64 * 69; idx += 512) vl[idx] = 0.0f;
  __syncthreads();

  // ---------------- pass 2: out[e,b] ----------------
  run_pass(w2f);

  #pragma unroll
  for (int bt = 0; bt < 2; ++bt)
    #pragma unroll
    for (int r = 0; r < 16; ++r) {
      const int rr = (r & 3) + 8 * (r >> 2) + 4 * half;
      atomicAdd(&vl[(kt * 32 + rr) * 69 + bt * 32 + col], vacc[bt][r]);
    }
  __syncthreads();

  for (int idx = t; idx < 64 * 64; idx += 512) {
    int s = idx >> 6, e = idx & 63;
    out[(base + s) * 64 + e] = vl[e * 69 + s] * 0.125f;
  }
}

extern "C" void kernel_launch(void* const* d_in, const int* in_sizes, int n_in,
                              void* d_out, int out_size, void* d_ws, size_t ws_size,
                              hipStream_t stream) {
  const float* x = (const float*)d_in[0];
  const float* g = (const float*)d_in[1];
  const float* W = (const float*)d_in[2];
  float* o = (float*)d_out;
  u16* w1f = (u16*)d_ws;
  u16* w2f = w1f + 65 * 4096;
  hipLaunchKernelGGL(prep_w, dim3(65), dim3(256), 0, stream, W, w1f, w2f);
  hipLaunchKernelGGL(rquad_main, dim3(512), dim3(512), 0, stream, x, g, w1f, w2f, o);
}

// Round 5
// 122.791 us; speedup vs baseline: 1.2272x; 1.0977x over previous
//
#include <hip/hip_runtime.h>
#include <stdint.h>

typedef __bf16    bf16x8  __attribute__((ext_vector_type(8)));
typedef float     f32x16v __attribute__((ext_vector_type(16)));
typedef float     f32x4v  __attribute__((ext_vector_type(4)));
typedef uint32_t  u32x4v  __attribute__((ext_vector_type(4)));
typedef unsigned short u16;

__device__ __forceinline__ u16 f32_to_bf16_rne(float f) {
  uint32_t u = __builtin_bit_cast(uint32_t, f);
  return (u16)((u + 0x7fffu + ((u >> 16) & 1u)) >> 16);
}

__device__ __forceinline__ f32x16v mfma16(u32x4v a, u32x4v b, f32x16v c) {
  return __builtin_amdgcn_mfma_f32_32x32x16_bf16(
      __builtin_bit_cast(bf16x8, a), __builtin_bit_cast(bf16x8, b), c, 0, 0, 0);
}

// prep: W f32 [65][i=64][k=64] -> fragment-major bf16 arrays (B-operand form).
// elem idx = jj*4096 + (c*4+s)*512 + l*8 + e  (l = lane, c = 32-col tile)
//   w1f: W[jj][ i=s*16+(l>>5)*8+e ][ k=c*32+(l&31) ]
//   w2f: W[jj][ e_row=c*32+(l&31) ][ k=s*16+(l>>5)*8+e ]
__global__ __launch_bounds__(256) void prep_w(const float* __restrict__ W,
                                              u16* __restrict__ w1f,
                                              u16* __restrict__ w2f) {
  __shared__ float Wl[4096];
  const int jj = blockIdx.x;
  const int t  = threadIdx.x;
  for (int idx = t; idx < 4096; idx += 256) Wl[idx] = W[jj * 4096 + idx];
  __syncthreads();
  for (int p = t; p < 512; p += 256) {
    const int c2 = p >> 6, l = p & 63;
    const int ct = c2 >> 2, s = c2 & 3;
    const int rowA = ct * 32 + (l & 31);
    const int k0   = s * 16 + (l >> 5) * 8;
    u16 v1[8], v2[8];
    #pragma unroll
    for (int e = 0; e < 8; ++e) {
      v2[e] = f32_to_bf16_rne(Wl[rowA * 64 + k0 + e]);
      v1[e] = f32_to_bf16_rne(Wl[(k0 + e) * 64 + rowA]);
    }
    u32x4v pk1, pk2;
    #pragma unroll
    for (int q = 0; q < 4; ++q) {
      pk1[q] = (uint32_t)v1[2*q] | ((uint32_t)v1[2*q+1] << 16);
      pk2[q] = (uint32_t)v2[2*q] | ((uint32_t)v2[2*q+1] << 16);
    }
    *reinterpret_cast<u32x4v*>(w1f + jj * 4096 + p * 8) = pk1;
    *reinterpret_cast<u32x4v*>(w2f + jj * 4096 + p * 8) = pk2;
  }
}

// main: grid 1024 x 256 thr (4 waves), 32 samples/block, wave = j-quarter.
// Samples in A rows: A[b,K]=x1[b,j]*g[b,i] built in-regs (8 mul + 4 cvt per
// MFMA-pair); B = pure W fragments; accumulator stays in MFMA C across all j.
__global__ __launch_bounds__(256, 4) void rquad_main(
    const float* __restrict__ x, const float* __restrict__ g,
    const u16* __restrict__ w1f, const u16* __restrict__ w2f,
    float* __restrict__ out) {
  __shared__ float x1f[32 * 67];   // x1 f32 [sample][j], odd stride
  __shared__ float vl [32 * 68];   // combine buffer [sample][k], 16B-aligned rows

  const int t    = threadIdx.x;
  const int lane = t & 63;
  const int jq   = t >> 6;          // wave id = j-quarter
  const int bl   = lane & 31;       // sample row within tile
  const int half = lane >> 5;       // K-chunk half
  const long base = (long)blockIdx.x * 32;
  const int rot  = (int)((blockIdx.x * 23u) % 65u);

  for (int idx = t; idx < 32 * 64; idx += 256) {
    int s = idx >> 6, c = idx & 63;
    x1f[s * 67 + c] = x[(base + s) * 64 + c];
  }
  if (t < 32) x1f[t * 67 + 64] = 1.0f;   // bias
  for (int idx = t; idx < 32 * 68; idx += 256) vl[idx] = 0.0f;

  // per-lane K-side slice (g for pass1): ka[s]=g[b, s*16+half*8 ..+4), kb next 4
  f32x4v ka[4], kb[4];
  #pragma unroll
  for (int s = 0; s < 4; ++s) {
    const float* gp = g + (base + bl) * 64 + s * 16 + half * 8;
    ka[s] = *reinterpret_cast<const f32x4v*>(gp);
    kb[s] = *reinterpret_cast<const f32x4v*>(gp + 4);
  }

  const int j0 = jq * 16;
  const int jn = (jq == 3) ? 17 : 16;

  f32x16v acc0, acc1;

  __syncthreads();

  auto run_pass = [&](const u16* __restrict__ Wsrc) {
    #pragma unroll
    for (int r = 0; r < 16; ++r) { acc0[r] = 0.0f; acc1[r] = 0.0f; }
    const u16* wl = Wsrc + lane * 8;
    for (int i = 0; i < jn; ++i) {
      int jj = j0 + i + rot; if (jj >= 65) jj -= 65;
      const u16* wj = wl + jj * 4096;
      // 8 B-frags (2 col-tiles x 4 K-steps), each a contiguous 1KB wave-load
      u32x4v b00 = *reinterpret_cast<const u32x4v*>(wj);
      u32x4v b01 = *reinterpret_cast<const u32x4v*>(wj + 512);
      u32x4v b02 = *reinterpret_cast<const u32x4v*>(wj + 1024);
      u32x4v b03 = *reinterpret_cast<const u32x4v*>(wj + 1536);
      u32x4v b10 = *reinterpret_cast<const u32x4v*>(wj + 2048);
      u32x4v b11 = *reinterpret_cast<const u32x4v*>(wj + 2560);
      u32x4v b12 = *reinterpret_cast<const u32x4v*>(wj + 3072);
      u32x4v b13 = *reinterpret_cast<const u32x4v*>(wj + 3584);
      const float xs = x1f[bl * 67 + jj];
      u32x4v av[4];
      #pragma unroll
      for (int s = 0; s < 4; ++s) {
        float m0 = xs * ka[s][0], m1 = xs * ka[s][1];
        float m2 = xs * ka[s][2], m3 = xs * ka[s][3];
        float m4 = xs * kb[s][0], m5 = xs * kb[s][1];
        float m6 = xs * kb[s][2], m7 = xs * kb[s][3];
        uint32_t p0, p1, p2, p3;
        asm("v_cvt_pk_bf16_f32 %0, %1, %2" : "=v"(p0) : "v"(m0), "v"(m1));
        asm("v_cvt_pk_bf16_f32 %0, %1, %2" : "=v"(p1) : "v"(m2), "v"(m3));
        asm("v_cvt_pk_bf16_f32 %0, %1, %2" : "=v"(p2) : "v"(m4), "v"(m5));
        asm("v_cvt_pk_bf16_f32 %0, %1, %2" : "=v"(p3) : "v"(m6), "v"(m7));
        av[s][0] = p0; av[s][1] = p1; av[s][2] = p2; av[s][3] = p3;
      }
      acc0 = mfma16(av[0], b00, acc0);
      acc1 = mfma16(av[0], b10, acc1);
      acc0 = mfma16(av[1], b01, acc0);
      acc1 = mfma16(av[1], b11, acc1);
      acc0 = mfma16(av[2], b02, acc0);
      acc1 = mfma16(av[2], b12, acc1);
      acc0 = mfma16(av[3], b03, acc0);
      acc1 = mfma16(av[3], b13, acc1);
    }
  };

  // ---------------- pass 1: v[b,k] ----------------
  run_pass(w1f);

  #pragma unroll
  for (int r = 0; r < 16; ++r) {
    const int rr = (r & 3) + 8 * (r >> 2) + 4 * half;   // sample row
    atomicAdd(&vl[rr * 68 + bl],      acc0[r]);
    atomicAdd(&vl[rr * 68 + 32 + bl], acc1[r]);
  }
  __syncthreads();

  // reload K-side slice <- v (f32)
  #pragma unroll
  for (int s = 0; s < 4; ++s) {
    const float* vp = &vl[bl * 68 + s * 16 + half * 8];
    ka[s] = *reinterpret_cast<const f32x4v*>(vp);
    kb[s] = *reinterpret_cast<const f32x4v*>(vp + 4);
  }
  __syncthreads();
  for (int idx = t; idx < 32 * 68; idx += 256) vl[idx] = 0.0f;
  __syncthreads();

  // ---------------- pass 2: out[b,e] ----------------
  run_pass(w2f);

  #pragma unroll
  for (int r = 0; r < 16; ++r) {
    const int rr = (r & 3) + 8 * (r >> 2) + 4 * half;
    atomicAdd(&vl[rr * 68 + bl],      acc0[r]);
    atomicAdd(&vl[rr * 68 + 32 + bl], acc1[r]);
  }
  __syncthreads();

  for (int idx = t; idx < 32 * 64; idx += 256) {
    int s = idx >> 6, e = idx & 63;
    out[(base + s) * 64 + e] = vl[s * 68 + e] * 0.125f;
  }
}

extern "C" void kernel_launch(void* const* d_in, const int* in_sizes, int n_in,
                              void* d_out, int out_size, void* d_ws, size_t ws_size,
                              hipStream_t stream) {
  const float* x = (const float*)d_in[0];
  const float* g = (const float*)d_in[1];
  const float* W = (const float*)d_in[2];
  float* o = (float*)d_out;
  u16* w1f = (u16*)d_ws;
  u16* w2f = w1f + 65 * 4096;
  hipLaunchKernelGGL(prep_w, dim3(65), dim3(256), 0, stream, W, w1f, w2f);
  hipLaunchKernelGGL(rquad_main, dim3(1024), dim3(256), 0, stream, x, g, w1f, w2f, o);
}